// Round 6
// baseline (172.622 us; speedup 1.0000x reference)
//
#include <hip/hip_runtime.h>
#include <hip/hip_bf16.h>

#define N_NODES 100000
#define N_EDGES 1600000
#define D 128

#define NBINS 196       // ceil(100000 / 512)
#define BINSHIFT 9      // 512 nodes per bin
#define BINCAP 10000    // avg 8163 edges/bin
#define EPB 8192        // edges per bin-phase block

// k_prep block layout: [0,196) bin, [196,204) W image, [204,3329) X cvt
#define PREP_BIN_BLOCKS 196
#define PREP_W_BLOCKS 8
#define PREP_CVT_BLOCKS 3125   // 100000*128 / (512*8)

typedef __bf16 bf16x8 __attribute__((ext_vector_type(8)));
typedef short short8 __attribute__((ext_vector_type(8)));
typedef float f32x4 __attribute__((ext_vector_type(4)));

__device__ __forceinline__ unsigned short f2bf(float f) {
  union { float f; unsigned u; } c; c.f = f;
  unsigned u = c.u;
  u += 0x7FFFu + ((u >> 16) & 1u);   // round-to-nearest-even
  return (unsigned short)(u >> 16);
}
__device__ __forceinline__ float bflo(unsigned u) {
  union { unsigned u; float f; } c; c.u = u << 16; return c.f;
}
__device__ __forceinline__ float bfhi(unsigned u) {
  union { unsigned u; float f; } c; c.u = u & 0xFFFF0000u; return c.f;
}

// ============ k_prep: fused edge binning (FIRST) + W image + X cvt ==========
// binbuf entry packs (dst&511)<<17 | src  (src < 2^17, 26 bits total)
#define PADK 136

__launch_bounds__(512)
__global__ void k_prep(const float* __restrict__ X, unsigned short* __restrict__ Xb,
                       const float* __restrict__ W1, const float* __restrict__ W2,
                       unsigned short* __restrict__ Wimg,
                       const int* __restrict__ esrc, const int* __restrict__ edst,
                       int* __restrict__ g_bincnt, unsigned* __restrict__ binbuf) {
  __shared__ int cnt[NBINS];
  __shared__ int base[NBINS];
  const int b = blockIdx.x, t = threadIdx.x;

  if (b < PREP_BIN_BLOCKS) {
    // ---- edge binning: starts at t=0 on ~196 CUs ----
    const int e0 = b * EPB;
    const int ne = min(EPB, N_EDGES - e0);
    for (int i = t; i < NBINS; i += 512) cnt[i] = 0;
    __syncthreads();
    for (int i = t; i < ne; i += 512)
      atomicAdd(&cnt[edst[e0 + i] >> BINSHIFT], 1);
    __syncthreads();
    for (int i = t; i < NBINS; i += 512) {
      base[i] = atomicAdd(&g_bincnt[i], cnt[i]);
      cnt[i] = 0;
    }
    __syncthreads();
    for (int i = t; i < ne; i += 512) {
      int d = edst[e0 + i];
      int s = esrc[e0 + i];
      int bi = d >> BINSHIFT;
      int pos = base[bi] + atomicAdd(&cnt[bi], 1);
      binbuf[(size_t)bi * BINCAP + pos] = ((unsigned)(d & 511) << 17) | (unsigned)s;
    }
    return;
  }
  if (b < PREP_BIN_BLOCKS + PREP_W_BLOCKS) {
    int bb = b - PREP_BIN_BLOCKS;
    const float* W = (bb & 4) ? W2 : W1;
    unsigned short* img = Wimg + ((bb & 4) ? 128 * PADK : 0);
    int k0 = (bb & 3) * 32;
#pragma unroll
    for (int it = 0; it < 8; ++it) {
      int idx = it * 512 + t;                 // 4096 entries: 32 k x 128 n
      int k = k0 + (idx >> 7), n = idx & 127;
      img[n * PADK + k] = f2bf(W[k * 128 + n]);
    }
    return;
  }
  // ---- X f32 -> bf16 ----
  size_t i = ((size_t)(b - PREP_BIN_BLOCKS - PREP_W_BLOCKS) * 512 + t) * 8;
  const float4* p = (const float4*)(X + i);
  float4 a = p[0], c = p[1];
  short8 s;
  s[0] = f2bf(a.x); s[1] = f2bf(a.y); s[2] = f2bf(a.z); s[3] = f2bf(a.w);
  s[4] = f2bf(c.x); s[5] = f2bf(c.y); s[6] = f2bf(c.z); s[7] = f2bf(c.w);
  *(short8*)(Xb + i) = s;
}

// ============ k_binsort: per-bin counting sort + deg/offs (START semantics) =
__launch_bounds__(512)
__global__ void k_binsort(const unsigned* __restrict__ binbuf, const int* __restrict__ g_bincnt,
                          int* __restrict__ srt, int* __restrict__ deg,
                          int* __restrict__ offs) {
  __shared__ int hist[512];
  __shared__ int scan[512];
  __shared__ int sb[256];
  const int b = blockIdx.x, t = threadIdx.x;

  // exclusive prefix over bin counts (all blocks compute it; ~free)
  if (t < 256) sb[t] = (t < NBINS) ? g_bincnt[t] : 0;
  __syncthreads();
  for (int d = 1; d < 256; d <<= 1) {
    int x = 0;
    if (t < 256 && t >= d) x = sb[t - d];
    __syncthreads();
    if (t < 256) sb[t] += x;
    __syncthreads();
  }
  const int cntb = g_bincnt[b];
  const int gbase = (b == 0) ? 0 : sb[b - 1];
  const int n0 = b << BINSHIFT;
  const unsigned* ebuf = binbuf + (size_t)b * BINCAP;

  hist[t] = 0;
  __syncthreads();
  for (int i = t; i < cntb; i += 512)
    atomicAdd(&hist[ebuf[i] >> 17], 1);
  __syncthreads();
  int v = hist[t];
  scan[t] = v;
  __syncthreads();
  for (int d = 1; d < 512; d <<= 1) {
    int x = (t >= d) ? scan[t - d] : 0;
    __syncthreads();
    scan[t] += x;
    __syncthreads();
  }
  int n = n0 + t;
  if (n < N_NODES) {
    deg[n] = v;
    offs[n] = gbase + scan[t] - v;   // segment start
  }
  hist[t] = scan[t] - v;             // reuse as bin-local write cursor
  __syncthreads();
  for (int i = t; i < cntb; i += 512) {
    unsigned e = ebuf[i];
    int pos = atomicAdd(&hist[e >> 17], 1);
    srt[gbase + pos] = (int)(e & 0x1FFFFu);
  }
}

// ============ k_gmlp: fused gather + MLP, 128 rows/block, 2 blocks/CU =======
// Wave owns a 16-row stripe end-to-end: gathers 16 nodes into lH, GEMM1 from
// lH (A) x lW1 (B), ReLU->h1 back into the SAME stripe (no barrier needed),
// GEMM2 with B straight from global W2 image (L2-resident). One barrier total.
__launch_bounds__(512, 4)
__global__ void k_gmlp(const unsigned* __restrict__ X1,
                       const int* __restrict__ deg, const int* __restrict__ offs,
                       const int* __restrict__ srt,
                       const unsigned short* __restrict__ Wimg,
                       const float* __restrict__ b1v, const float* __restrict__ b2v,
                       float* __restrict__ out) {
  __shared__ __attribute__((aligned(16))) unsigned short lW1[128 * PADK];
  __shared__ __attribute__((aligned(16))) unsigned short lH[128 * PADK];

  const int t = threadIdx.x;
  const int wave = t >> 6, lane = t & 63;
  const int row0 = blockIdx.x * 128;

  // stage W1 image (first half of Wimg), 2176 uint4s
  {
    const uint4* wi = (const uint4*)Wimg;
    uint4* lw = (uint4*)lW1;
    for (int i = t; i < (128 * PADK * 2) / 16; i += 512) lw[i] = wi[i];
  }

  // ---- gather phase: wave handles its 16 nodes ----
  for (int j = 0; j < 16; ++j) {
    int lrow = wave * 16 + j;
    int node = row0 + lrow;
    unsigned pack = 0;
    if (node < N_NODES) {
      unsigned u = X1[(size_t)node * 64 + lane];
      float hx = bflo(u), hy = bfhi(u);
      int e = offs[node];
      int end = e + deg[node];
      for (; e + 8 <= end; e += 8) {
        int s0 = srt[e],     s1 = srt[e + 1], s2 = srt[e + 2], s3 = srt[e + 3];
        int s4 = srt[e + 4], s5 = srt[e + 5], s6 = srt[e + 6], s7 = srt[e + 7];
        unsigned u0 = X1[(size_t)s0 * 64 + lane];
        unsigned u1 = X1[(size_t)s1 * 64 + lane];
        unsigned u2 = X1[(size_t)s2 * 64 + lane];
        unsigned u3 = X1[(size_t)s3 * 64 + lane];
        unsigned u4 = X1[(size_t)s4 * 64 + lane];
        unsigned u5 = X1[(size_t)s5 * 64 + lane];
        unsigned u6 = X1[(size_t)s6 * 64 + lane];
        unsigned u7 = X1[(size_t)s7 * 64 + lane];
        hx += bflo(u0); hy += bfhi(u0);
        hx += bflo(u1); hy += bfhi(u1);
        hx += bflo(u2); hy += bfhi(u2);
        hx += bflo(u3); hy += bfhi(u3);
        hx += bflo(u4); hy += bfhi(u4);
        hx += bflo(u5); hy += bfhi(u5);
        hx += bflo(u6); hy += bfhi(u6);
        hx += bflo(u7); hy += bfhi(u7);
      }
      for (; e + 2 <= end; e += 2) {
        unsigned u0 = X1[(size_t)srt[e] * 64 + lane];
        unsigned u1 = X1[(size_t)srt[e + 1] * 64 + lane];
        hx += bflo(u0); hy += bfhi(u0);
        hx += bflo(u1); hy += bfhi(u1);
      }
      for (; e < end; ++e) {
        unsigned u0 = X1[(size_t)srt[e] * 64 + lane];
        hx += bflo(u0); hy += bfhi(u0);
      }
      pack = ((unsigned)f2bf(hy) << 16) | f2bf(hx);
    }
    *(unsigned*)&lH[lrow * PADK + lane * 2] = pack;
  }

  __syncthreads();   // covers lW1 staging + (uniformity) gather completion

  // ---- GEMM1: rows = own stripe, A from lH, B from lW1 ----
  const int lr = lane & 15, lg = lane >> 4;
  bf16x8 a[4];
#pragma unroll
  for (int kb = 0; kb < 4; ++kb)
    a[kb] = *(const bf16x8*)&lH[(wave * 16 + lr) * PADK + kb * 32 + lg * 8];

  f32x4 acc[8];
#pragma unroll
  for (int nc = 0; nc < 8; ++nc) {
    float bb = b1v[nc * 16 + lr];
    acc[nc] = (f32x4){bb, bb, bb, bb};
  }
#pragma unroll
  for (int nc = 0; nc < 8; ++nc) {
#pragma unroll
    for (int kb = 0; kb < 4; ++kb) {
      bf16x8 b = *(const bf16x8*)&lW1[(nc * 16 + lr) * PADK + kb * 32 + lg * 8];
      acc[nc] = __builtin_amdgcn_mfma_f32_16x16x32_bf16(a[kb], b, acc[nc], 0, 0, 0);
    }
  }

  // ---- ReLU -> h1 back into own stripe (intra-wave dependency only) ----
#pragma unroll
  for (int nc = 0; nc < 8; ++nc) {
#pragma unroll
    for (int r = 0; r < 4; ++r) {
      float v = acc[nc][r];
      v = v > 0.f ? v : 0.f;
      lH[(wave * 16 + lg * 4 + r) * PADK + nc * 16 + lr] = f2bf(v);
    }
  }

  // ---- GEMM2: A from lH (own stripe), B from global W2 image ----
  bf16x8 a2[4];
#pragma unroll
  for (int kb = 0; kb < 4; ++kb)
    a2[kb] = *(const bf16x8*)&lH[(wave * 16 + lr) * PADK + kb * 32 + lg * 8];

#pragma unroll
  for (int nc = 0; nc < 8; ++nc) {
    float bb = b2v[nc * 16 + lr];
    acc[nc] = (f32x4){bb, bb, bb, bb};
  }
  const unsigned short* W2i = Wimg + 128 * PADK;
#pragma unroll
  for (int nc = 0; nc < 8; ++nc) {
#pragma unroll
    for (int kb = 0; kb < 4; ++kb) {
      bf16x8 b = *(const bf16x8*)&W2i[(nc * 16 + lr) * PADK + kb * 32 + lg * 8];
      acc[nc] = __builtin_amdgcn_mfma_f32_16x16x32_bf16(a2[kb], b, acc[nc], 0, 0, 0);
    }
  }

  // ---- store f32 ----
#pragma unroll
  for (int nc = 0; nc < 8; ++nc) {
#pragma unroll
    for (int r = 0; r < 4; ++r) {
      int row = row0 + wave * 16 + lg * 4 + r;
      if (row < N_NODES) out[(size_t)row * D + nc * 16 + lr] = acc[nc][r];
    }
  }
}

// ================= old CSR build (fallback path, end-semantics offs) ========

__global__ void k_hist(const int* __restrict__ dst, int* __restrict__ deg) {
  int i = blockIdx.x * 256 + threadIdx.x;
  if (i < N_EDGES) atomicAdd(&deg[dst[i]], 1);
}

__global__ void k_scan1(const int* __restrict__ deg, int* __restrict__ offs,
                        int* __restrict__ bsum) {
  __shared__ int s[1024];
  int t = threadIdx.x;
  int i = blockIdx.x * 1024 + t;
  int v = (i < N_NODES) ? deg[i] : 0;
  s[t] = v;
  __syncthreads();
  for (int d = 1; d < 1024; d <<= 1) {
    int x = (t >= d) ? s[t - d] : 0;
    __syncthreads();
    s[t] += x;
    __syncthreads();
  }
  if (i < N_NODES) offs[i] = s[t] - v;
  if (t == 1023) bsum[blockIdx.x] = s[t];
}

__global__ void k_scan2(int* __restrict__ bsum) {
  __shared__ int s[128];
  int t = threadIdx.x;
  int v = (t < 98) ? bsum[t] : 0;
  s[t] = v;
  __syncthreads();
  for (int d = 1; d < 128; d <<= 1) {
    int x = (t >= d) ? s[t - d] : 0;
    __syncthreads();
    s[t] += x;
    __syncthreads();
  }
  if (t < 98) bsum[t] = s[t] - v;
}

__global__ void k_scan3(int* __restrict__ offs, const int* __restrict__ bsum) {
  int i = blockIdx.x * 1024 + threadIdx.x;
  if (i < N_NODES) offs[i] += bsum[blockIdx.x];
}

__global__ void k_bucket(const int* __restrict__ src, const int* __restrict__ dst,
                         int* __restrict__ offs, int* __restrict__ srt) {
  int i = blockIdx.x * 256 + threadIdx.x;
  if (i < N_EDGES) {
    int pos = atomicAdd(&offs[dst[i]], 1);
    srt[pos] = src[i];
  }
}

// ------------- f32 fallback gather (END-semantics offs) -------------
__global__ void k_gather(const float* __restrict__ X, const int* __restrict__ deg,
                         const int* __restrict__ offs, const int* __restrict__ srt,
                         float* __restrict__ out) {
  int node = blockIdx.x * 4 + (threadIdx.x >> 6);
  int lane = threadIdx.x & 63;
  const float2* X2 = (const float2*)X;
  float2 h = X2[(size_t)node * 64 + lane];
  int end = offs[node];
  int dg = deg[node];
  for (int e = end - dg; e < end; ++e) {
    int s = srt[e];
    float2 x = X2[(size_t)s * 64 + lane];
    h.x += x.x; h.y += x.y;
  }
  ((float2*)out)[(size_t)node * 64 + lane] = h;
}

// ------------- fallback fused MLP (f32 h0 in d_out, in-place) -------------
#define BR 256

__launch_bounds__(512, 1)
__global__ void k_mlp(const float* __restrict__ h0,
                      const float* __restrict__ W1, const float* __restrict__ b1,
                      const float* __restrict__ W2, const float* __restrict__ b2,
                      float* __restrict__ out) {
  __shared__ __attribute__((aligned(16))) unsigned short lW[2 * 128 * PADK];
  __shared__ __attribute__((aligned(16))) unsigned short lH[BR * PADK];

  const int t = threadIdx.x;
  const int wave = t >> 6, lane = t & 63;
  const int lr = lane & 15, lg = lane >> 4;
  const int row0 = blockIdx.x * BR;
  const int wrow = row0 + wave * 32;

  for (int i = t; i < 128 * 128; i += 512) {
    int k = i >> 7, n = i & 127;
    lW[n * PADK + k] = f2bf(W1[i]);
    lW[128 * PADK + n * PADK + k] = f2bf(W2[i]);
  }

  bf16x8 a[2][4];
#pragma unroll
  for (int tr = 0; tr < 2; ++tr) {
#pragma unroll
    for (int kb = 0; kb < 4; ++kb) {
      int r = wrow + tr * 16 + lr;
      if (r >= N_NODES) r = N_NODES - 1;
      const float4* p = (const float4*)(h0 + (size_t)r * D + kb * 32 + lg * 8);
      float4 f0 = p[0], f1 = p[1];
      short8 s;
      s[0] = f2bf(f0.x); s[1] = f2bf(f0.y); s[2] = f2bf(f0.z); s[3] = f2bf(f0.w);
      s[4] = f2bf(f1.x); s[5] = f2bf(f1.y); s[6] = f2bf(f1.z); s[7] = f2bf(f1.w);
      a[tr][kb] = __builtin_bit_cast(bf16x8, s);
    }
  }

  f32x4 acc[2][8];
#pragma unroll
  for (int nc = 0; nc < 8; ++nc) {
    float bb = b1[nc * 16 + lr];
#pragma unroll
    for (int tr = 0; tr < 2; ++tr) acc[tr][nc] = (f32x4){bb, bb, bb, bb};
  }

  __syncthreads();

#pragma unroll
  for (int nc = 0; nc < 8; ++nc) {
#pragma unroll
    for (int kb = 0; kb < 4; ++kb) {
      bf16x8 b = *(const bf16x8*)&lW[(nc * 16 + lr) * PADK + kb * 32 + lg * 8];
#pragma unroll
      for (int tr = 0; tr < 2; ++tr)
        acc[tr][nc] = __builtin_amdgcn_mfma_f32_16x16x32_bf16(a[tr][kb], b, acc[tr][nc], 0, 0, 0);
    }
  }

#pragma unroll
  for (int tr = 0; tr < 2; ++tr) {
#pragma unroll
    for (int nc = 0; nc < 8; ++nc) {
#pragma unroll
      for (int r = 0; r < 4; ++r) {
        float v = acc[tr][nc][r];
        v = v > 0.f ? v : 0.f;
        int lrow = wave * 32 + tr * 16 + lg * 4 + r;
        lH[lrow * PADK + nc * 16 + lr] = f2bf(v);
      }
    }
  }

  __syncthreads();

  bf16x8 a2[2][4];
#pragma unroll
  for (int tr = 0; tr < 2; ++tr) {
#pragma unroll
    for (int kb = 0; kb < 4; ++kb)
      a2[tr][kb] = *(const bf16x8*)&lH[(wave * 32 + tr * 16 + lr) * PADK + kb * 32 + lg * 8];
  }

#pragma unroll
  for (int nc = 0; nc < 8; ++nc) {
    float bb = b2[nc * 16 + lr];
#pragma unroll
    for (int tr = 0; tr < 2; ++tr) acc[tr][nc] = (f32x4){bb, bb, bb, bb};
  }

#pragma unroll
  for (int nc = 0; nc < 8; ++nc) {
#pragma unroll
    for (int kb = 0; kb < 4; ++kb) {
      bf16x8 b = *(const bf16x8*)&lW[128 * PADK + (nc * 16 + lr) * PADK + kb * 32 + lg * 8];
#pragma unroll
      for (int tr = 0; tr < 2; ++tr)
        acc[tr][nc] = __builtin_amdgcn_mfma_f32_16x16x32_bf16(a2[tr][kb], b, acc[tr][nc], 0, 0, 0);
    }
  }

#pragma unroll
  for (int tr = 0; tr < 2; ++tr) {
#pragma unroll
    for (int nc = 0; nc < 8; ++nc) {
#pragma unroll
      for (int r = 0; r < 4; ++r) {
        int row = wrow + tr * 16 + lg * 4 + r;
        if (row < N_NODES) out[(size_t)row * D + nc * 16 + lr] = acc[tr][nc][r];
      }
    }
  }
}

extern "C" void kernel_launch(void* const* d_in, const int* in_sizes, int n_in,
                              void* d_out, int out_size, void* d_ws, size_t ws_size,
                              hipStream_t stream) {
  const float* X  = (const float*)d_in[0];
  const float* W1 = (const float*)d_in[1];
  const float* b1 = (const float*)d_in[2];
  const float* W2 = (const float*)d_in[3];
  const float* b2 = (const float*)d_in[4];
  const int* esrc = (const int*)d_in[5];
  const int* edst = (const int*)d_in[6];
  float* out = (float*)d_out;

  char* ws = (char*)d_ws;
  int* deg      = (int*)(ws);                    // 400,000 B
  int* offs     = (int*)(ws + 400000);           // 400,000 B
  int* g_bincnt = (int*)(ws + 800000);           // 1 KB (also bsum in fallback)
  int* srt      = (int*)(ws + 802048);           // 6.4 MB -> 7,202,048
  unsigned short* Xb  = (unsigned short*)(ws + 7202048);   // 25.6 MB -> 32,802,048
  unsigned* binbuf = (unsigned*)(ws + 32802048); // 7.84 MB
  unsigned short* Wimg = (unsigned short*)(ws + 58402048); // 69,632 B padded bf16 W image
  const size_t NEED = 58471680;

  if (ws_size >= NEED) {
    hipMemsetAsync(g_bincnt, 0, NBINS * sizeof(int), stream);
    k_prep<<<PREP_BIN_BLOCKS + PREP_W_BLOCKS + PREP_CVT_BLOCKS, 512, 0, stream>>>(
        X, Xb, W1, W2, Wimg, esrc, edst, g_bincnt, binbuf);
    k_binsort<<<NBINS, 512, 0, stream>>>(binbuf, g_bincnt, srt, deg, offs);
    k_gmlp<<<(N_NODES + 127) / 128, 512, 0, stream>>>((const unsigned*)Xb, deg, offs, srt,
                                                      Wimg, b1, b2, out);
  } else {
    // fallback: proven round-1 pipeline (f32 gather, END-semantics offs)
    int* bsum = g_bincnt;
    hipMemsetAsync(deg, 0, N_NODES * sizeof(int), stream);
    k_hist  <<<N_EDGES / 256, 256, 0, stream>>>(edst, deg);
    k_scan1 <<<98, 1024, 0, stream>>>(deg, offs, bsum);
    k_scan2 <<<1, 128, 0, stream>>>(bsum);
    k_scan3 <<<98, 1024, 0, stream>>>(offs, bsum);
    k_bucket<<<N_EDGES / 256, 256, 0, stream>>>(esrc, edst, offs, srt);
    k_gather<<<N_NODES / 4, 256, 0, stream>>>(X, deg, offs, srt, out);
    k_mlp   <<<(N_NODES + BR - 1) / BR, 512, 0, stream>>>(out, W1, b1, W2, b2, out);
  }
}

// Round 7
// 133.329 us; speedup vs baseline: 1.2947x; 1.2947x over previous
//
#include <hip/hip_runtime.h>
#include <hip/hip_bf16.h>

#define N_NODES 100000
#define N_EDGES 1600000
#define D 128

#define NBINS 196       // ceil(100000 / 512)
#define BINSHIFT 9      // 512 nodes per bin
#define BINCAP 10000    // avg 8163 edges/bin
#define EPB 8192        // edges per bin-phase block

// k_mid block layout: [0,196) binsort, [196,204) W image, [204,3329) X cvt
#define MID_SORT_BLOCKS 196
#define MID_W_BLOCKS 8
#define MID_CVT_BLOCKS 3125    // 100000*128 / (512*8)

#define PADK 136

typedef __bf16 bf16x8 __attribute__((ext_vector_type(8)));
typedef short short8 __attribute__((ext_vector_type(8)));
typedef float f32x4 __attribute__((ext_vector_type(4)));

__device__ __forceinline__ unsigned short f2bf(float f) {
  union { float f; unsigned u; } c; c.f = f;
  unsigned u = c.u;
  u += 0x7FFFu + ((u >> 16) & 1u);   // round-to-nearest-even
  return (unsigned short)(u >> 16);
}
__device__ __forceinline__ float bflo(unsigned u) {
  union { unsigned u; float f; } c; c.u = u << 16; return c.f;
}
__device__ __forceinline__ float bfhi(unsigned u) {
  union { unsigned u; float f; } c; c.u = u & 0xFFFF0000u; return c.f;
}

// ============ k_bin: edge binning; packs (dst&511)<<17 | src ================
__launch_bounds__(512)
__global__ void k_bin(const int* __restrict__ esrc, const int* __restrict__ edst,
                      int* __restrict__ g_bincnt, unsigned* __restrict__ binbuf) {
  __shared__ int cnt[NBINS];
  __shared__ int base[NBINS];
  const int b = blockIdx.x, t = threadIdx.x;
  const int e0 = b * EPB;
  const int ne = min(EPB, N_EDGES - e0);
  for (int i = t; i < NBINS; i += 512) cnt[i] = 0;
  __syncthreads();
  for (int i = t; i < ne; i += 512)
    atomicAdd(&cnt[edst[e0 + i] >> BINSHIFT], 1);
  __syncthreads();
  for (int i = t; i < NBINS; i += 512) {
    base[i] = atomicAdd(&g_bincnt[i], cnt[i]);
    cnt[i] = 0;
  }
  __syncthreads();
  for (int i = t; i < ne; i += 512) {
    int d = edst[e0 + i];
    int s = esrc[e0 + i];
    int bi = d >> BINSHIFT;
    int pos = base[bi] + atomicAdd(&cnt[bi], 1);
    binbuf[(size_t)bi * BINCAP + pos] = ((unsigned)(d & 511) << 17) | (unsigned)s;
  }
}

// ============ k_mid: fused binsort + W image + X cvt ========================
__launch_bounds__(512)
__global__ void k_mid(const unsigned* __restrict__ binbuf, const int* __restrict__ g_bincnt,
                      int* __restrict__ srt, int* __restrict__ deg, int* __restrict__ offs,
                      const float* __restrict__ X, unsigned short* __restrict__ Xb,
                      const float* __restrict__ W1, const float* __restrict__ W2,
                      unsigned short* __restrict__ Wimg) {
  const int b = blockIdx.x, t = threadIdx.x;

  if (b < MID_SORT_BLOCKS) {
    // ---- per-bin counting sort; emits deg/offs (START semantics) ----
    __shared__ int hist[512];
    __shared__ int scan[512];
    __shared__ int sb[256];
    if (t < 256) sb[t] = (t < NBINS) ? g_bincnt[t] : 0;
    __syncthreads();
    for (int d = 1; d < 256; d <<= 1) {
      int x = 0;
      if (t < 256 && t >= d) x = sb[t - d];
      __syncthreads();
      if (t < 256) sb[t] += x;
      __syncthreads();
    }
    const int cntb = g_bincnt[b];
    const int gbase = (b == 0) ? 0 : sb[b - 1];
    const int n0 = b << BINSHIFT;
    const unsigned* ebuf = binbuf + (size_t)b * BINCAP;

    hist[t] = 0;
    __syncthreads();
    for (int i = t; i < cntb; i += 512)
      atomicAdd(&hist[ebuf[i] >> 17], 1);
    __syncthreads();
    int v = hist[t];
    scan[t] = v;
    __syncthreads();
    for (int d = 1; d < 512; d <<= 1) {
      int x = (t >= d) ? scan[t - d] : 0;
      __syncthreads();
      scan[t] += x;
      __syncthreads();
    }
    int n = n0 + t;
    if (n < N_NODES) {
      deg[n] = v;
      offs[n] = gbase + scan[t] - v;   // segment start
    }
    hist[t] = scan[t] - v;             // bin-local write cursor
    __syncthreads();
    for (int i = t; i < cntb; i += 512) {
      unsigned e = ebuf[i];
      int pos = atomicAdd(&hist[e >> 17], 1);
      srt[gbase + pos] = (int)(e & 0x1FFFFu);
    }
    return;
  }
  if (b < MID_SORT_BLOCKS + MID_W_BLOCKS) {
    int bb = b - MID_SORT_BLOCKS;
    const float* W = (bb & 4) ? W2 : W1;
    unsigned short* img = Wimg + ((bb & 4) ? 128 * PADK : 0);
    int k0 = (bb & 3) * 32;
#pragma unroll
    for (int it = 0; it < 8; ++it) {
      int idx = it * 512 + t;                 // 4096 entries: 32 k x 128 n
      int k = k0 + (idx >> 7), n = idx & 127;
      img[n * PADK + k] = f2bf(W[k * 128 + n]);
    }
    return;
  }
  // ---- X f32 -> bf16 ----
  size_t i = ((size_t)(b - MID_SORT_BLOCKS - MID_W_BLOCKS) * 512 + t) * 8;
  const float4* p = (const float4*)(X + i);
  float4 a = p[0], c = p[1];
  short8 s;
  s[0] = f2bf(a.x); s[1] = f2bf(a.y); s[2] = f2bf(a.z); s[3] = f2bf(a.w);
  s[4] = f2bf(c.x); s[5] = f2bf(c.y); s[6] = f2bf(c.z); s[7] = f2bf(c.w);
  *(short8*)(Xb + i) = s;
}

// ------------- aggregation (bf16, START-semantics offs), 8-deep unroll ------
__global__ void k_gather_bf(const unsigned int* __restrict__ X1,
                            const int* __restrict__ deg, const int* __restrict__ offs,
                            const int* __restrict__ srt, unsigned int* __restrict__ h0) {
  int node = blockIdx.x * 4 + (threadIdx.x >> 6);
  int lane = threadIdx.x & 63;
  unsigned u = X1[(size_t)node * 64 + lane];
  float hx = bflo(u), hy = bfhi(u);
  int e = offs[node];
  int end = e + deg[node];
  for (; e + 8 <= end; e += 8) {
    int s0 = srt[e],     s1 = srt[e + 1], s2 = srt[e + 2], s3 = srt[e + 3];
    int s4 = srt[e + 4], s5 = srt[e + 5], s6 = srt[e + 6], s7 = srt[e + 7];
    unsigned u0 = X1[(size_t)s0 * 64 + lane];
    unsigned u1 = X1[(size_t)s1 * 64 + lane];
    unsigned u2 = X1[(size_t)s2 * 64 + lane];
    unsigned u3 = X1[(size_t)s3 * 64 + lane];
    unsigned u4 = X1[(size_t)s4 * 64 + lane];
    unsigned u5 = X1[(size_t)s5 * 64 + lane];
    unsigned u6 = X1[(size_t)s6 * 64 + lane];
    unsigned u7 = X1[(size_t)s7 * 64 + lane];
    hx += bflo(u0); hy += bfhi(u0);
    hx += bflo(u1); hy += bfhi(u1);
    hx += bflo(u2); hy += bfhi(u2);
    hx += bflo(u3); hy += bfhi(u3);
    hx += bflo(u4); hy += bfhi(u4);
    hx += bflo(u5); hy += bfhi(u5);
    hx += bflo(u6); hy += bfhi(u6);
    hx += bflo(u7); hy += bfhi(u7);
  }
  for (; e + 2 <= end; e += 2) {
    unsigned u0 = X1[(size_t)srt[e] * 64 + lane];
    unsigned u1 = X1[(size_t)srt[e + 1] * 64 + lane];
    hx += bflo(u0); hy += bfhi(u0);
    hx += bflo(u1); hy += bfhi(u1);
  }
  for (; e < end; ++e) {
    unsigned u0 = X1[(size_t)srt[e] * 64 + lane];
    hx += bflo(u0); hy += bfhi(u0);
  }
  h0[(size_t)node * 64 + lane] = ((unsigned)f2bf(hy) << 16) | f2bf(hx);
}

// ============ k_mlp2: BR=128, 8 waves (wave owns 16 rows), 2 blocks/CU ======
// LDS: one W buffer (stage W1 -> GEMM1 -> barrier -> restage W2 -> GEMM2)
// + lH for h1. A-frags from global bf16 h0b; B always from LDS.
#define BR2 128

__launch_bounds__(512, 4)
__global__ void k_mlp2(const unsigned short* __restrict__ h0,
                       const unsigned short* __restrict__ Wimg,
                       const float* __restrict__ b1v, const float* __restrict__ b2v,
                       float* __restrict__ out) {
  __shared__ __attribute__((aligned(16))) unsigned short lW[128 * PADK];
  __shared__ __attribute__((aligned(16))) unsigned short lH[BR2 * PADK];

  const int t = threadIdx.x;
  const int wave = t >> 6, lane = t & 63;
  const int lr = lane & 15, lg = lane >> 4;
  const int row0 = blockIdx.x * BR2;
  const int wrow = row0 + wave * 16;

  // stage W1 image (2176 uint4)
  {
    const uint4* wi = (const uint4*)Wimg;
    uint4* lw = (uint4*)lW;
    for (int i = t; i < (128 * PADK * 2) / 16; i += 512) lw[i] = wi[i];
  }

  // A fragments from global bf16 h0
  bf16x8 a[4];
#pragma unroll
  for (int kb = 0; kb < 4; ++kb) {
    int r = wrow + lr;
    if (r >= N_NODES) r = N_NODES - 1;          // clamp; result unused
    a[kb] = __builtin_bit_cast(bf16x8,
        *(const short8*)(h0 + (size_t)r * D + kb * 32 + lg * 8));
  }

  f32x4 acc[8];
#pragma unroll
  for (int nc = 0; nc < 8; ++nc) {
    float bb = b1v[nc * 16 + lr];
    acc[nc] = (f32x4){bb, bb, bb, bb};
  }

  __syncthreads();   // W1 staged

  // GEMM1
#pragma unroll
  for (int nc = 0; nc < 8; ++nc) {
#pragma unroll
    for (int kb = 0; kb < 4; ++kb) {
      bf16x8 b = *(const bf16x8*)&lW[(nc * 16 + lr) * PADK + kb * 32 + lg * 8];
      acc[nc] = __builtin_amdgcn_mfma_f32_16x16x32_bf16(a[kb], b, acc[nc], 0, 0, 0);
    }
  }

  __syncthreads();   // everyone done reading W1

  // restage W2 into same buffer
  {
    const uint4* wi = (const uint4*)Wimg + 2176;
    uint4* lw = (uint4*)lW;
    for (int i = t; i < 2176; i += 512) lw[i] = wi[i];
  }

  // ReLU -> h1 into own stripe (intra-wave dependency only)
#pragma unroll
  for (int nc = 0; nc < 8; ++nc) {
#pragma unroll
    for (int r = 0; r < 4; ++r) {
      float v = acc[nc][r];
      v = v > 0.f ? v : 0.f;
      lH[(wave * 16 + lg * 4 + r) * PADK + nc * 16 + lr] = f2bf(v);
    }
  }

  __syncthreads();   // W2 staged (and h1 visible, though only own stripe read)

  bf16x8 a2[4];
#pragma unroll
  for (int kb = 0; kb < 4; ++kb)
    a2[kb] = *(const bf16x8*)&lH[(wave * 16 + lr) * PADK + kb * 32 + lg * 8];

#pragma unroll
  for (int nc = 0; nc < 8; ++nc) {
    float bb = b2v[nc * 16 + lr];
    acc[nc] = (f32x4){bb, bb, bb, bb};
  }

  // GEMM2
#pragma unroll
  for (int nc = 0; nc < 8; ++nc) {
#pragma unroll
    for (int kb = 0; kb < 4; ++kb) {
      bf16x8 b = *(const bf16x8*)&lW[(nc * 16 + lr) * PADK + kb * 32 + lg * 8];
      acc[nc] = __builtin_amdgcn_mfma_f32_16x16x32_bf16(a2[kb], b, acc[nc], 0, 0, 0);
    }
  }

  // store f32
#pragma unroll
  for (int nc = 0; nc < 8; ++nc) {
#pragma unroll
    for (int r = 0; r < 4; ++r) {
      int row = wrow + lg * 4 + r;
      if (row < N_NODES) out[(size_t)row * D + nc * 16 + lr] = acc[nc][r];
    }
  }
}

// ================= old CSR build (fallback path, end-semantics offs) ========

__global__ void k_hist(const int* __restrict__ dst, int* __restrict__ deg) {
  int i = blockIdx.x * 256 + threadIdx.x;
  if (i < N_EDGES) atomicAdd(&deg[dst[i]], 1);
}

__global__ void k_scan1(const int* __restrict__ deg, int* __restrict__ offs,
                        int* __restrict__ bsum) {
  __shared__ int s[1024];
  int t = threadIdx.x;
  int i = blockIdx.x * 1024 + t;
  int v = (i < N_NODES) ? deg[i] : 0;
  s[t] = v;
  __syncthreads();
  for (int d = 1; d < 1024; d <<= 1) {
    int x = (t >= d) ? s[t - d] : 0;
    __syncthreads();
    s[t] += x;
    __syncthreads();
  }
  if (i < N_NODES) offs[i] = s[t] - v;
  if (t == 1023) bsum[blockIdx.x] = s[t];
}

__global__ void k_scan2(int* __restrict__ bsum) {
  __shared__ int s[128];
  int t = threadIdx.x;
  int v = (t < 98) ? bsum[t] : 0;
  s[t] = v;
  __syncthreads();
  for (int d = 1; d < 128; d <<= 1) {
    int x = (t >= d) ? s[t - d] : 0;
    __syncthreads();
    s[t] += x;
    __syncthreads();
  }
  if (t < 98) bsum[t] = s[t] - v;
}

__global__ void k_scan3(int* __restrict__ offs, const int* __restrict__ bsum) {
  int i = blockIdx.x * 1024 + threadIdx.x;
  if (i < N_NODES) offs[i] += bsum[blockIdx.x];
}

__global__ void k_bucket(const int* __restrict__ src, const int* __restrict__ dst,
                         int* __restrict__ offs, int* __restrict__ srt) {
  int i = blockIdx.x * 256 + threadIdx.x;
  if (i < N_EDGES) {
    int pos = atomicAdd(&offs[dst[i]], 1);
    srt[pos] = src[i];
  }
}

// ------------- f32 fallback gather (END-semantics offs) -------------
__global__ void k_gather(const float* __restrict__ X, const int* __restrict__ deg,
                         const int* __restrict__ offs, const int* __restrict__ srt,
                         float* __restrict__ out) {
  int node = blockIdx.x * 4 + (threadIdx.x >> 6);
  int lane = threadIdx.x & 63;
  const float2* X2 = (const float2*)X;
  float2 h = X2[(size_t)node * 64 + lane];
  int end = offs[node];
  int dg = deg[node];
  for (int e = end - dg; e < end; ++e) {
    int s = srt[e];
    float2 x = X2[(size_t)s * 64 + lane];
    h.x += x.x; h.y += x.y;
  }
  ((float2*)out)[(size_t)node * 64 + lane] = h;
}

// ------------- fallback fused MLP (f32 h0 in d_out, in-place) -------------
#define BR 256

__launch_bounds__(512, 1)
__global__ void k_mlp(const float* __restrict__ h0,
                      const float* __restrict__ W1, const float* __restrict__ b1,
                      const float* __restrict__ W2, const float* __restrict__ b2,
                      float* __restrict__ out) {
  __shared__ __attribute__((aligned(16))) unsigned short lW[2 * 128 * PADK];
  __shared__ __attribute__((aligned(16))) unsigned short lH[BR * PADK];

  const int t = threadIdx.x;
  const int wave = t >> 6, lane = t & 63;
  const int lr = lane & 15, lg = lane >> 4;
  const int row0 = blockIdx.x * BR;
  const int wrow = row0 + wave * 32;

  for (int i = t; i < 128 * 128; i += 512) {
    int k = i >> 7, n = i & 127;
    lW[n * PADK + k] = f2bf(W1[i]);
    lW[128 * PADK + n * PADK + k] = f2bf(W2[i]);
  }

  bf16x8 a[2][4];
#pragma unroll
  for (int tr = 0; tr < 2; ++tr) {
#pragma unroll
    for (int kb = 0; kb < 4; ++kb) {
      int r = wrow + tr * 16 + lr;
      if (r >= N_NODES) r = N_NODES - 1;
      const float4* p = (const float4*)(h0 + (size_t)r * D + kb * 32 + lg * 8);
      float4 f0 = p[0], f1 = p[1];
      short8 s;
      s[0] = f2bf(f0.x); s[1] = f2bf(f0.y); s[2] = f2bf(f0.z); s[3] = f2bf(f0.w);
      s[4] = f2bf(f1.x); s[5] = f2bf(f1.y); s[6] = f2bf(f1.z); s[7] = f2bf(f1.w);
      a[tr][kb] = __builtin_bit_cast(bf16x8, s);
    }
  }

  f32x4 acc[2][8];
#pragma unroll
  for (int nc = 0; nc < 8; ++nc) {
    float bb = b1[nc * 16 + lr];
#pragma unroll
    for (int tr = 0; tr < 2; ++tr) acc[tr][nc] = (f32x4){bb, bb, bb, bb};
  }

  __syncthreads();

#pragma unroll
  for (int nc = 0; nc < 8; ++nc) {
#pragma unroll
    for (int kb = 0; kb < 4; ++kb) {
      bf16x8 b = *(const bf16x8*)&lW[(nc * 16 + lr) * PADK + kb * 32 + lg * 8];
#pragma unroll
      for (int tr = 0; tr < 2; ++tr)
        acc[tr][nc] = __builtin_amdgcn_mfma_f32_16x16x32_bf16(a[tr][kb], b, acc[tr][nc], 0, 0, 0);
    }
  }

#pragma unroll
  for (int tr = 0; tr < 2; ++tr) {
#pragma unroll
    for (int nc = 0; nc < 8; ++nc) {
#pragma unroll
      for (int r = 0; r < 4; ++r) {
        float v = acc[tr][nc][r];
        v = v > 0.f ? v : 0.f;
        int lrow = wave * 32 + tr * 16 + lg * 4 + r;
        lH[lrow * PADK + nc * 16 + lr] = f2bf(v);
      }
    }
  }

  __syncthreads();

  bf16x8 a2[2][4];
#pragma unroll
  for (int tr = 0; tr < 2; ++tr) {
#pragma unroll
    for (int kb = 0; kb < 4; ++kb)
      a2[tr][kb] = *(const bf16x8*)&lH[(wave * 32 + tr * 16 + lr) * PADK + kb * 32 + lg * 8];
  }

#pragma unroll
  for (int nc = 0; nc < 8; ++nc) {
    float bb = b2[nc * 16 + lr];
#pragma unroll
    for (int tr = 0; tr < 2; ++tr) acc[tr][nc] = (f32x4){bb, bb, bb, bb};
  }

#pragma unroll
  for (int nc = 0; nc < 8; ++nc) {
#pragma unroll
    for (int kb = 0; kb < 4; ++kb) {
      bf16x8 b = *(const bf16x8*)&lW[128 * PADK + (nc * 16 + lr) * PADK + kb * 32 + lg * 8];
#pragma unroll
      for (int tr = 0; tr < 2; ++tr)
        acc[tr][nc] = __builtin_amdgcn_mfma_f32_16x16x32_bf16(a2[tr][kb], b, acc[tr][nc], 0, 0, 0);
    }
  }

#pragma unroll
  for (int tr = 0; tr < 2; ++tr) {
#pragma unroll
    for (int nc = 0; nc < 8; ++nc) {
#pragma unroll
      for (int r = 0; r < 4; ++r) {
        int row = wrow + tr * 16 + lg * 4 + r;
        if (row < N_NODES) out[(size_t)row * D + nc * 16 + lr] = acc[tr][nc][r];
      }
    }
  }
}

extern "C" void kernel_launch(void* const* d_in, const int* in_sizes, int n_in,
                              void* d_out, int out_size, void* d_ws, size_t ws_size,
                              hipStream_t stream) {
  const float* X  = (const float*)d_in[0];
  const float* W1 = (const float*)d_in[1];
  const float* b1 = (const float*)d_in[2];
  const float* W2 = (const float*)d_in[3];
  const float* b2 = (const float*)d_in[4];
  const int* esrc = (const int*)d_in[5];
  const int* edst = (const int*)d_in[6];
  float* out = (float*)d_out;

  char* ws = (char*)d_ws;
  int* deg      = (int*)(ws);                    // 400,000 B
  int* offs     = (int*)(ws + 400000);           // 400,000 B
  int* g_bincnt = (int*)(ws + 800000);           // 1 KB (also bsum in fallback)
  int* srt      = (int*)(ws + 802048);           // 6.4 MB -> 7,202,048
  unsigned short* Xb  = (unsigned short*)(ws + 7202048);   // 25.6 MB -> 32,802,048
  unsigned short* h0b = (unsigned short*)(ws + 32802048);  // 25.6 MB -> 58,402,048
  unsigned* binbuf = (unsigned*)(ws + 32802048); // 7.84 MB, aliases h0b (dead by gather)
  unsigned short* Wimg = (unsigned short*)(ws + 58402048); // 69,632 B padded bf16 W image
  const size_t NEED = 58471680;

  if (ws_size >= NEED) {
    hipMemsetAsync(g_bincnt, 0, NBINS * sizeof(int), stream);
    k_bin<<<(N_EDGES + EPB - 1) / EPB, 512, 0, stream>>>(esrc, edst, g_bincnt, binbuf);
    k_mid<<<MID_SORT_BLOCKS + MID_W_BLOCKS + MID_CVT_BLOCKS, 512, 0, stream>>>(
        binbuf, g_bincnt, srt, deg, offs, X, Xb, W1, W2, Wimg);
    k_gather_bf<<<N_NODES / 4, 256, 0, stream>>>((const unsigned*)Xb, deg, offs, srt,
                                                 (unsigned*)h0b);
    k_mlp2<<<(N_NODES + BR2 - 1) / BR2, 512, 0, stream>>>(h0b, Wimg, b1, b2, out);
  } else {
    // fallback: proven round-1 pipeline (f32 gather, END-semantics offs)
    int* bsum = g_bincnt;
    hipMemsetAsync(deg, 0, N_NODES * sizeof(int), stream);
    k_hist  <<<N_EDGES / 256, 256, 0, stream>>>(edst, deg);
    k_scan1 <<<98, 1024, 0, stream>>>(deg, offs, bsum);
    k_scan2 <<<1, 128, 0, stream>>>(bsum);
    k_scan3 <<<98, 1024, 0, stream>>>(offs, bsum);
    k_bucket<<<N_EDGES / 256, 256, 0, stream>>>(esrc, edst, offs, srt);
    k_gather<<<N_NODES / 4, 256, 0, stream>>>(X, deg, offs, srt, out);
    k_mlp   <<<(N_NODES + BR - 1) / BR, 512, 0, stream>>>(out, W1, b1, W2, b2, out);
  }
}